// Round 4
// baseline (1929.012 us; speedup 1.0000x reference)
//
#include <hip/hip_runtime.h>
#include <cstdint>
#include <cstddef>

// Problem dims (fixed by the reference)
constexpr int L_ = 6, B_ = 4, S_ = 1024, D_ = 1024, H_ = 16, FF_ = 4096;
constexpr int D3_ = 3 * D_;   // 3072
constexpr int HD_ = D_ / H_;  // 64

typedef float f32x4 __attribute__((ext_vector_type(4)));
typedef __bf16 bf16x8 __attribute__((ext_vector_type(8)));
typedef unsigned short u16;
typedef u16 u16x4 __attribute__((ext_vector_type(4)));
typedef u16 u16x8 __attribute__((ext_vector_type(8)));

__device__ __forceinline__ u16 f2bf(float f) {
    union { float f; uint32_t u; } v; v.f = f;
    uint32_t r = v.u + 0x7FFFu + ((v.u >> 16) & 1u);   // RNE
    return (u16)(r >> 16);
}

// async global->LDS, 16B per lane; LDS dest is wave-uniform base + lane*16
__device__ __forceinline__ void gload16(const void* g, void* l) {
    __builtin_amdgcn_global_load_lds(
        (const __attribute__((address_space(1))) unsigned int*)g,
        (__attribute__((address_space(3))) unsigned int*)l,
        16, 0, 0);
}

// ---------------------------------------------------------------------------
// Per-layer weight prep: fp32 W[K][N] -> bf16 W^T[N][K] for all 4 matrices
// in ONE dispatch (grid 3072 blocks of 256).  Tile ranges:
//   [0,768)    qkv  K=1024 N=3072  (48 x 16 tiles)
//   [768,1024) out  K=1024 N=1024  (16 x 16)
//   [1024,2048) fc1 K=1024 N=4096  (64 x 16)
//   [2048,3072) fc2 K=4096 N=1024  (16 x 64)
// ---------------------------------------------------------------------------
__global__ __launch_bounds__(256) void cvt_layer(
    const float* __restrict__ qw, const float* __restrict__ ow,
    const float* __restrict__ f1w, const float* __restrict__ f2w,
    u16* __restrict__ tq, u16* __restrict__ to,
    u16* __restrict__ t1, u16* __restrict__ t2)
{
    __shared__ float tile[64][65];
    const int bid = blockIdx.x, tid = threadIdx.x;
    const float* W; u16* WT; int K, N, bn, bk;
    if (bid < 768)       { W = qw;  WT = tq; K = 1024; N = 3072; int t = bid;        bn = (t % 48) * 64; bk = (t / 48) * 64; }
    else if (bid < 1024) { W = ow;  WT = to; K = 1024; N = 1024; int t = bid - 768;  bn = (t % 16) * 64; bk = (t / 16) * 64; }
    else if (bid < 2048) { W = f1w; WT = t1; K = 1024; N = 4096; int t = bid - 1024; bn = (t % 64) * 64; bk = (t / 64) * 64; }
    else                 { W = f2w; WT = t2; K = 4096; N = 1024; int t = bid - 2048; bn = (t % 16) * 64; bk = (t / 16) * 64; }
    #pragma unroll
    for (int i = 0; i < 16; ++i) {
        int idx = i * 256 + tid;
        int r = idx >> 6, c = idx & 63;
        tile[r][c] = W[(size_t)(bk + r) * N + bn + c];
    }
    __syncthreads();
    #pragma unroll
    for (int i = 0; i < 16; ++i) {
        int idx = i * 256 + tid;
        int r = idx >> 6, c = idx & 63;
        WT[(size_t)(bn + r) * K + bk + c] = f2bf(tile[c][r]);
    }
}

// ---------------------------------------------------------------------------
// V transpose: qkv[B*S][3D] (v at col 2D)  ->  vt[(b*H+h)*HD + hd][S]  (bf16)
// grid: (S/64, B*H), block 256
// ---------------------------------------------------------------------------
__global__ __launch_bounds__(256) void vt_transpose(
    const u16* __restrict__ qkv, u16* __restrict__ vt)
{
    __shared__ u16 tile[64][72];
    const int tid = threadIdx.x;
    const int s0 = blockIdx.x * 64, bh = blockIdx.y;
    const int b = bh >> 4, h = bh & 15;
    #pragma unroll
    for (int i = 0; i < 2; ++i) {
        int idx = tid + i * 256;
        int r = idx >> 3, c8 = (idx & 7) * 8;
        u16x8 v = *(const u16x8*)(qkv + ((size_t)(b * S_ + s0 + r)) * D3_ + 2 * D_ + h * 64 + c8);
        #pragma unroll
        for (int j = 0; j < 8; ++j) tile[c8 + j][r] = v[j];
    }
    __syncthreads();
    #pragma unroll
    for (int i = 0; i < 2; ++i) {
        int idx = tid + i * 256;
        int r = idx >> 3, c8 = (idx & 7) * 8;
        u16x8 v;
        #pragma unroll
        for (int j = 0; j < 8; ++j) v[j] = tile[r][c8 + j];
        *(u16x8*)(vt + ((size_t)(bh * 64 + r)) * S_ + s0 + c8) = v;
    }
}

// ---------------------------------------------------------------------------
// LayerNorm row kernel: fp32 X row (1024) -> bf16 xn.  grid: B*S, block 256.
// ---------------------------------------------------------------------------
__global__ __launch_bounds__(256) void ln_kernel(
    const float* __restrict__ X, const float* __restrict__ g,
    const float* __restrict__ bp, u16* __restrict__ out)
{
    const int row = blockIdx.x, tid = threadIdx.x;
    const float* xr = X + (size_t)row * D_;
    f32x4 v = *(const f32x4*)(xr + tid * 4);
    float s  = v[0] + v[1] + v[2] + v[3];
    float s2 = v[0]*v[0] + v[1]*v[1] + v[2]*v[2] + v[3]*v[3];
    #pragma unroll
    for (int off = 32; off >= 1; off >>= 1) {
        s  += __shfl_down(s,  off);
        s2 += __shfl_down(s2, off);
    }
    __shared__ float red[8];
    const int lane = tid & 63, wid = tid >> 6;
    if (lane == 0) { red[wid] = s; red[4 + wid] = s2; }
    __syncthreads();
    s  = red[0] + red[1] + red[2] + red[3];
    s2 = red[4] + red[5] + red[6] + red[7];
    float mean = s * (1.f / D_);
    float var  = s2 * (1.f / D_) - mean * mean;     // == mean((x-m)^2)
    float rstd = rsqrtf(var + 1e-5f);
    f32x4 gv = *(const f32x4*)(g  + tid * 4);
    f32x4 bv = *(const f32x4*)(bp + tid * 4);
    u16x4 o4;
    #pragma unroll
    for (int r = 0; r < 4; ++r) o4[r] = f2bf((v[r] - mean) * rstd * gv[r] + bv[r]);
    *(u16x4*)(out + (size_t)row * D_ + tid * 4) = o4;
}

// ---------------------------------------------------------------------------
// gemm256d: C[M][N] = A[M][K] * B^T[N][K], bf16 in, fp32 acc.
// 256x256 tile, BK=32, 8 waves (2M x 4N, per-wave C = 128x64), 4-deep
// LDS pipeline (4 x 32 KiB buffers = 128 KiB).
// T3+T4: ONE s_barrier per K-tile; counted vmcnt(8) in steady state (tile t's
// 4 loads drain, t+1/t+2's 8 stay in flight; tail vmcnt(4)/vmcnt(0)); tile
// t's body issues stage loads for tile t+3 split A/B across the two MFMA
// phases.  Race-free by construction: buffer (t+3)&3 was last read in tile
// t-1, whose reads completed before tile t's barrier.
// T2: XOR swizzle slot = chunk ^ ((row>>1)&3), applied on BOTH sides
// (pre-swizzled global source + swizzled ds_read slot) -> 0 conflicts (r2-
// verified).  T5: setprio around each 16-MFMA cluster.
// MODE: 0=+bias->bf16 (QKV), 1=+bias,pad-mask,atomic X+= (out-proj),
//       2=+bias,GELU->bf16 (FC1), 3=+bias,atomic X+= (FC2)
// ---------------------------------------------------------------------------
template<int MODE>
__global__ __launch_bounds__(512, 2) void gemm256d(
    const u16* __restrict__ A, const u16* __restrict__ BT,
    const float* __restrict__ bias,
    u16* __restrict__ Cb, float* __restrict__ X,
    const int* __restrict__ lengths,
    int M, int N, int K)
{
    __shared__ __align__(16) char lds[4][32768];   // [buf][A 16K | B 16K]
    const int tid = threadIdx.x;
    const int lane = tid & 63;
    const int w = tid >> 6;
    const int grp = lane >> 4, l15 = lane & 15;
    const int wm = w >> 2, wn = w & 3;
    const int m0 = blockIdx.y * 256, n0 = blockIdx.x * 256;
    const int Kh = K / gridDim.z;
    const int k0 = blockIdx.z * Kh;
    const int NT = Kh >> 5;                        // K-tiles of 32

    // staging: each wave stages A rows w*32..+31 and B rows w*32..+31
    // (2 issues each; per issue 64 lanes x 16B = 16 rows of 64B).
    const int lrow = lane >> 2;
    const int cchunk = (lane & 3) ^ ((lane >> 3) & 3);  // pre-swizzled source chunk
    const u16* gA = A  + (size_t)(m0 + w * 32 + lrow) * K + k0 + cchunk * 8;
    const u16* gB = BT + (size_t)(n0 + w * 32 + lrow) * K + k0 + cchunk * 8;
    const size_t row16 = (size_t)16 * K;
    char* const lA = &lds[0][0]     + w * 2048;
    char* const lB = &lds[0][16384] + w * 2048;
    const int rslot = (grp ^ ((l15 >> 1) & 3)) * 16;    // swizzled read slot

#define STAGE_A(t) do { const u16* p_ = gA + (size_t)(t) * 32;                 \
        char* l_ = lA + ((t) & 3) * 32768;                                     \
        gload16(p_, l_); gload16(p_ + row16, l_ + 1024); } while (0)
#define STAGE_B(t) do { const u16* p_ = gB + (size_t)(t) * 32;                 \
        char* l_ = lB + ((t) & 3) * 32768;                                     \
        gload16(p_, l_); gload16(p_ + row16, l_ + 1024); } while (0)

    f32x4 acc[8][4] = {};

    STAGE_A(0); STAGE_B(0);
    if (NT > 1) { STAGE_A(1); STAGE_B(1); }
    if (NT > 2) { STAGE_A(2); STAGE_B(2); }

    for (int t = 0; t < NT; ++t) {
        const int rem = NT - t;
        if (rem > 2)       asm volatile("s_waitcnt vmcnt(8)" ::: "memory");
        else if (rem == 2) asm volatile("s_waitcnt vmcnt(4)" ::: "memory");
        else               asm volatile("s_waitcnt vmcnt(0)" ::: "memory");
        __builtin_amdgcn_s_barrier();              // tile t fully resident
        __builtin_amdgcn_sched_barrier(0);
        const char* Ab = &lds[t & 3][0];
        const char* Bb = &lds[t & 3][16384];

        bf16x8 bfr[4], af0[4], af1[4];
        #pragma unroll
        for (int nf = 0; nf < 4; ++nf)
            bfr[nf] = *(const bf16x8*)(Bb + (wn * 64 + nf * 16 + l15) * 64 + rslot);
        #pragma unroll
        for (int mf = 0; mf < 4; ++mf)
            af0[mf] = *(const bf16x8*)(Ab + (wm * 128 + mf * 16 + l15) * 64 + rslot);
        if (t + 3 < NT) STAGE_A(t + 3);
        __builtin_amdgcn_s_setprio(1);
        #pragma unroll
        for (int mf = 0; mf < 4; ++mf)
            #pragma unroll
            for (int nf = 0; nf < 4; ++nf)
                acc[mf][nf] = __builtin_amdgcn_mfma_f32_16x16x32_bf16(
                    af0[mf], bfr[nf], acc[mf][nf], 0, 0, 0);
        __builtin_amdgcn_s_setprio(0);
        #pragma unroll
        for (int mf = 0; mf < 4; ++mf)
            af1[mf] = *(const bf16x8*)(Ab + (wm * 128 + 64 + mf * 16 + l15) * 64 + rslot);
        if (t + 3 < NT) STAGE_B(t + 3);
        __builtin_amdgcn_s_setprio(1);
        #pragma unroll
        for (int mf = 0; mf < 4; ++mf)
            #pragma unroll
            for (int nf = 0; nf < 4; ++nf)
                acc[4 + mf][nf] = __builtin_amdgcn_mfma_f32_16x16x32_bf16(
                    af1[mf], bfr[nf], acc[4 + mf][nf], 0, 0, 0);
        __builtin_amdgcn_s_setprio(0);
    }
#undef STAGE_A
#undef STAGE_B

    const float bscale = (k0 == 0) ? 1.f : 0.f;    // bias exactly once per output
    // C/D frag: col = lane&15, row = (lane>>4)*4 + reg  [HW-verified]
    #pragma unroll
    for (int mi = 0; mi < 8; ++mi) {
        int row_g = m0 + wm * 128 + mi * 16 + grp * 4;
        #pragma unroll
        for (int nf = 0; nf < 4; ++nf) {
            int col_g = n0 + wn * 64 + nf * 16 + l15;
            float bv = bias[col_g] * bscale;
            f32x4 v = acc[mi][nf];
            if constexpr (MODE == 0) {
                #pragma unroll
                for (int r = 0; r < 4; ++r)
                    Cb[(size_t)(row_g + r) * N + col_g] = f2bf(v[r] + bv);
            } else if constexpr (MODE == 2) {
                #pragma unroll
                for (int r = 0; r < 4; ++r) {
                    float t = v[r] + bv;
                    float ge = 0.5f * t * (1.f + erff(t * 0.70710678118654752f));
                    Cb[(size_t)(row_g + r) * N + col_g] = f2bf(ge);
                }
            } else if constexpr (MODE == 1) {
                int len = lengths[row_g >> 10];      // row_g%4==0: same batch
                #pragma unroll
                for (int r = 0; r < 4; ++r) {
                    int row = row_g + r;
                    float add = ((row & 1023) >= len) ? 0.f : (v[r] + bv);
                    atomicAdd(&X[(size_t)row * N + col_g], add);
                }
            } else {
                #pragma unroll
                for (int r = 0; r < 4; ++r)
                    atomicAdd(&X[(size_t)(row_g + r) * N + col_g], v[r] + bv);
            }
        }
    }
}

// ---------------------------------------------------------------------------
// Flash attention with rel_bias + causal + key-padding masks.
// grid: (S/64 q-tiles, B*H), block 256 (4 waves x 16 q-rows).
// Swapped QK^T (scores^T = K · Q^T) makes the softmax reduction lane-local and
// the P fragments feed the PV MFMA B-operand directly (k-slot bijection).
// O^T = V^T · P^T accumulated in fp32.
// ---------------------------------------------------------------------------
__global__ __launch_bounds__(256) void attn_kernel(
    const u16* __restrict__ qkv,     // [B*S][3D] bf16 (q | k | v)
    const u16* __restrict__ vt,      // [(b*H+h)*64 + hd][S] bf16
    const float* __restrict__ rel_bias, // [H][S][S] fp32
    const int* __restrict__ lengths,
    u16* __restrict__ obuf)          // [B*S][D] bf16
{
    __shared__ __align__(16) char kls[64 * 128];  // K tile  [kpos][hd], swizzled
    __shared__ __align__(16) char vls[64 * 128];  // V^T tile [hd][kpos], swizzled
    const int tid = threadIdx.x, lane = tid & 63, wid = tid >> 6;
    const int grp = lane >> 4, l15 = lane & 15;
    const int qt = blockIdx.x, bh = blockIdx.y;
    const int b = bh >> 4, h = bh & 15;
    const int len = lengths[b];
    const int qrow = qt * 64 + wid * 16 + l15;

    bf16x8 qf[2];
    {
        const u16* qp = qkv + ((size_t)(b * S_ + qrow)) * D3_ + h * 64 + grp * 8;
        qf[0] = *(const bf16x8*)qp;
        qf[1] = *(const bf16x8*)(qp + 32);
    }
    f32x4 oacc[4] = {};
    float m_run = -INFINITY, lsum = 0.f;
    int kt_end = (len + 63) >> 6;
    if (qt + 1 < kt_end) kt_end = qt + 1;   // causal trim

    for (int kt = 0; kt < kt_end; ++kt) {
        __syncthreads();
        #pragma unroll
        for (int i = 0; i < 2; ++i) {
            int id2 = tid + i * 256;
            int r = id2 >> 3, gg = id2 & 7;
            int sw = (r & 7) << 4;
            bf16x8 kv = *(const bf16x8*)(qkv + ((size_t)(b * S_ + kt * 64 + r)) * D3_ + D_ + h * 64 + gg * 8);
            *(bf16x8*)(kls + r * 128 + ((gg * 16) ^ sw)) = kv;
            bf16x8 vv = *(const bf16x8*)(vt + ((size_t)(bh * 64 + r)) * S_ + kt * 64 + gg * 8);
            *(bf16x8*)(vls + r * 128 + ((gg * 16) ^ sw)) = vv;
        }
        __syncthreads();

        // scores^T fragments: sf[f] covers kpos f*16..f*16+15 (rows), q (cols)
        f32x4 sf[4] = {};
        #pragma unroll
        for (int f = 0; f < 4; ++f) {
            int r = f * 16 + l15;
            int sw = (r & 7) << 4;
            #pragma unroll
            for (int t = 0; t < 2; ++t) {
                bf16x8 af = *(const bf16x8*)(kls + r * 128 + (((t * 32 + grp * 8) * 2) ^ sw));
                sf[f] = __builtin_amdgcn_mfma_f32_16x16x32_bf16(af, qf[t], sf[f], 0, 0, 0);
            }
        }
        // scale + rel_bias + causal + padding, then online softmax (per q = l15)
        float p[4][4];
        float tmax = -INFINITY;
        #pragma unroll
        for (int f = 0; f < 4; ++f) {
            f32x4 bi = *(const f32x4*)(rel_bias + ((size_t)h * S_ + qrow) * S_ + kt * 64 + f * 16 + grp * 4);
            #pragma unroll
            for (int r = 0; r < 4; ++r) {
                int kp = kt * 64 + f * 16 + grp * 4 + r;
                bool valid = (kp <= qrow) && (kp < len);
                float sv = valid ? fmaf(sf[f][r], 0.125f, bi[r]) : -INFINITY;
                p[f][r] = sv;
                tmax = fmaxf(tmax, sv);
            }
        }
        tmax = fmaxf(tmax, __shfl_xor(tmax, 16));
        tmax = fmaxf(tmax, __shfl_xor(tmax, 32));
        float m_new = fmaxf(m_run, tmax);
        float alpha = expf(m_run - m_new);   // 0 on first tile (m_run = -inf)
        float psum = 0.f;
        #pragma unroll
        for (int f = 0; f < 4; ++f)
            #pragma unroll
            for (int r = 0; r < 4; ++r) {
                float e = expf(p[f][r] - m_new);   // masked -> exp(-inf) = 0
                p[f][r] = e; psum += e;
            }
        psum += __shfl_xor(psum, 16);
        psum += __shfl_xor(psum, 32);
        lsum = lsum * alpha + psum;
        m_run = m_new;
        #pragma unroll
        for (int fo = 0; fo < 4; ++fo) {
            oacc[fo][0] *= alpha; oacc[fo][1] *= alpha;
            oacc[fo][2] *= alpha; oacc[fo][3] *= alpha;
        }
        // O^T += V^T · P^T ; k-slot bijection g(grp,j)=grp*4+(j&3)+16*(j>>2)
        #pragma unroll
        for (int t = 0; t < 2; ++t) {
            union { u16 u[8]; bf16x8 v; } pb;
            #pragma unroll
            for (int j = 0; j < 4; ++j) {
                pb.u[j]     = f2bf(p[2 * t][j]);
                pb.u[4 + j] = f2bf(p[2 * t + 1][j]);
            }
            #pragma unroll
            for (int fo = 0; fo < 4; ++fo) {
                int r = fo * 16 + l15;          // hd row of V^T
                int sw = (r & 7) << 4;
                union { u16x4 h4[2]; bf16x8 v; } av;
                av.h4[0] = *(const u16x4*)(vls + r * 128 + ((t * 64 + grp * 8)      ^ sw));
                av.h4[1] = *(const u16x4*)(vls + r * 128 + ((t * 64 + grp * 8 + 32) ^ sw));
                oacc[fo] = __builtin_amdgcn_mfma_f32_16x16x32_bf16(av.v, pb.v, oacc[fo], 0, 0, 0);
            }
        }
    }
    float inv = 1.f / lsum;
    #pragma unroll
    for (int fo = 0; fo < 4; ++fo)
        #pragma unroll
        for (int r = 0; r < 4; ++r) {
            int hd = fo * 16 + grp * 4 + r;
            obuf[((size_t)(b * S_) + qrow) * D_ + h * 64 + hd] = f2bf(oacc[fo][r] * inv);
        }
}

// ---------------------------------------------------------------------------
extern "C" void kernel_launch(void* const* d_in, const int* in_sizes, int n_in,
                              void* d_out, int out_size, void* d_ws, size_t ws_size,
                              hipStream_t stream)
{
    const float* x_in     = (const float*)d_in[0];
    const int*   lengths  = (const int*)d_in[1];
    const float* rel_bias = (const float*)d_in[2];
    const float* ln1_g    = (const float*)d_in[3];
    const float* ln1_b    = (const float*)d_in[4];
    const float* qkv_w    = (const float*)d_in[5];
    const float* qkv_b    = (const float*)d_in[6];
    const float* out_w    = (const float*)d_in[7];
    const float* out_b    = (const float*)d_in[8];
    const float* ln2_g    = (const float*)d_in[9];
    const float* ln2_b    = (const float*)d_in[10];
    const float* fc1_w    = (const float*)d_in[11];
    const float* fc1_b    = (const float*)d_in[12];
    const float* fc2_w    = (const float*)d_in[13];
    const float* fc2_b    = (const float*)d_in[14];
    float* X = (float*)d_out;     // running residual state, fp32

    char* ws = (char*)d_ws;
    size_t off = 0;
    auto alloc = [&](size_t bytes) {
        char* p = ws + off;
        off = (off + bytes + 255) & ~(size_t)255;
        return p;
    };
    u16* wT_qkv = (u16*)alloc((size_t)D3_ * D_ * 2);      // 6.3 MB (per-layer reuse)
    u16* wT_out = (u16*)alloc((size_t)D_ * D_ * 2);       // 2.1 MB
    u16* wT_fc1 = (u16*)alloc((size_t)FF_ * D_ * 2);      // 8.4 MB
    u16* wT_fc2 = (u16*)alloc((size_t)D_ * FF_ * 2);      // 8.4 MB
    u16* xn     = (u16*)alloc((size_t)B_ * S_ * D_ * 2);  // 8.4 MB
    u16* qkvb   = (u16*)alloc((size_t)B_ * S_ * D3_ * 2); // 25.2 MB
    u16* vtb    = (u16*)alloc((size_t)B_ * H_ * HD_ * S_ * 2); // 8.4 MB
    u16* ob     = (u16*)alloc((size_t)B_ * S_ * D_ * 2);  // 8.4 MB
    u16* h1     = (u16*)alloc((size_t)B_ * S_ * FF_ * 2); // 33.6 MB

    const int M = B_ * S_;  // 4096

    hipMemcpyAsync(X, x_in, (size_t)M * D_ * sizeof(float),
                   hipMemcpyDeviceToDevice, stream);

    for (int i = 0; i < L_; ++i) {
        // --- one-time weight convert+transpose (fp32 -> bf16 W^T), 1 dispatch ---
        cvt_layer<<<3072, 256, 0, stream>>>(
            qkv_w + (size_t)i * D_ * D3_, out_w + (size_t)i * D_ * D_,
            fc1_w + (size_t)i * D_ * FF_, fc2_w + (size_t)i * FF_ * D_,
            wT_qkv, wT_out, wT_fc1, wT_fc2);

        // --- attention sub-block ---
        ln_kernel<<<M, 256, 0, stream>>>(X, ln1_g + i * D_, ln1_b + i * D_, xn);
        gemm256d<0><<<dim3(D3_ / 256, M / 256, 1), 512, 0, stream>>>(
            xn, wT_qkv, qkv_b + (size_t)i * D3_, qkvb, nullptr, nullptr, M, D3_, D_);
        vt_transpose<<<dim3(S_ / 64, B_ * H_), 256, 0, stream>>>(qkvb, vtb);
        attn_kernel<<<dim3(S_ / 64, B_ * H_), 256, 0, stream>>>(
            qkvb, vtb, rel_bias, lengths, ob);
        gemm256d<1><<<dim3(D_ / 256, M / 256, 4), 512, 0, stream>>>(
            ob, wT_out, out_b + (size_t)i * D_, nullptr, X, lengths, M, D_, D_);

        // --- feed-forward sub-block ---
        ln_kernel<<<M, 256, 0, stream>>>(X, ln2_g + i * D_, ln2_b + i * D_, xn);
        gemm256d<2><<<dim3(FF_ / 256, M / 256, 1), 512, 0, stream>>>(
            xn, wT_fc1, fc1_b + (size_t)i * FF_, h1, nullptr, nullptr, M, FF_, D_);
        gemm256d<3><<<dim3(D_ / 256, M / 256, 4), 512, 0, stream>>>(
            h1, wT_fc2, fc2_b + (size_t)i * D_, nullptr, X, nullptr, M, D_, FF_);
    }
}

// Round 5
// 1903.629 us; speedup vs baseline: 1.0133x; 1.0133x over previous
//
#include <hip/hip_runtime.h>
#include <cstdint>
#include <cstddef>

// Problem dims (fixed by the reference)
constexpr int L_ = 6, B_ = 4, S_ = 1024, D_ = 1024, H_ = 16, FF_ = 4096;
constexpr int D3_ = 3 * D_;   // 3072
constexpr int HD_ = D_ / H_;  // 64

typedef float f32x4 __attribute__((ext_vector_type(4)));
typedef __bf16 bf16x8 __attribute__((ext_vector_type(8)));
typedef unsigned short u16;
typedef u16 u16x4 __attribute__((ext_vector_type(4)));
typedef u16 u16x8 __attribute__((ext_vector_type(8)));

__device__ __forceinline__ u16 f2bf(float f) {
    union { float f; uint32_t u; } v; v.f = f;
    uint32_t r = v.u + 0x7FFFu + ((v.u >> 16) & 1u);   // RNE
    return (u16)(r >> 16);
}

// async global->LDS, 16B per lane; LDS dest is wave-uniform base + lane*16
__device__ __forceinline__ void gload16(const void* g, void* l) {
    __builtin_amdgcn_global_load_lds(
        (const __attribute__((address_space(1))) unsigned int*)g,
        (__attribute__((address_space(3))) unsigned int*)l,
        16, 0, 0);
}

// ---------------------------------------------------------------------------
// Per-layer weight prep: fp32 W[K][N] -> bf16 W^T[N][K] for all 4 matrices
// in ONE dispatch (grid 3072 blocks of 256).
// ---------------------------------------------------------------------------
__global__ __launch_bounds__(256) void cvt_layer(
    const float* __restrict__ qw, const float* __restrict__ ow,
    const float* __restrict__ f1w, const float* __restrict__ f2w,
    u16* __restrict__ tq, u16* __restrict__ to,
    u16* __restrict__ t1, u16* __restrict__ t2)
{
    __shared__ float tile[64][65];
    const int bid = blockIdx.x, tid = threadIdx.x;
    const float* W; u16* WT; int K, N, bn, bk;
    if (bid < 768)       { W = qw;  WT = tq; K = 1024; N = 3072; int t = bid;        bn = (t % 48) * 64; bk = (t / 48) * 64; }
    else if (bid < 1024) { W = ow;  WT = to; K = 1024; N = 1024; int t = bid - 768;  bn = (t % 16) * 64; bk = (t / 16) * 64; }
    else if (bid < 2048) { W = f1w; WT = t1; K = 1024; N = 4096; int t = bid - 1024; bn = (t % 64) * 64; bk = (t / 64) * 64; }
    else                 { W = f2w; WT = t2; K = 4096; N = 1024; int t = bid - 2048; bn = (t % 16) * 64; bk = (t / 16) * 64; }
    #pragma unroll
    for (int i = 0; i < 16; ++i) {
        int idx = i * 256 + tid;
        int r = idx >> 6, c = idx & 63;
        tile[r][c] = W[(size_t)(bk + r) * N + bn + c];
    }
    __syncthreads();
    #pragma unroll
    for (int i = 0; i < 16; ++i) {
        int idx = i * 256 + tid;
        int r = idx >> 6, c = idx & 63;
        WT[(size_t)(bn + r) * K + bk + c] = f2bf(tile[c][r]);
    }
}

// ---------------------------------------------------------------------------
// V transpose: qkv[B*S][3D] (v at col 2D)  ->  vt[(b*H+h)*HD + hd][S]  (bf16)
// ---------------------------------------------------------------------------
__global__ __launch_bounds__(256) void vt_transpose(
    const u16* __restrict__ qkv, u16* __restrict__ vt)
{
    __shared__ u16 tile[64][72];
    const int tid = threadIdx.x;
    const int s0 = blockIdx.x * 64, bh = blockIdx.y;
    const int b = bh >> 4, h = bh & 15;
    #pragma unroll
    for (int i = 0; i < 2; ++i) {
        int idx = tid + i * 256;
        int r = idx >> 3, c8 = (idx & 7) * 8;
        u16x8 v = *(const u16x8*)(qkv + ((size_t)(b * S_ + s0 + r)) * D3_ + 2 * D_ + h * 64 + c8);
        #pragma unroll
        for (int j = 0; j < 8; ++j) tile[c8 + j][r] = v[j];
    }
    __syncthreads();
    #pragma unroll
    for (int i = 0; i < 2; ++i) {
        int idx = tid + i * 256;
        int r = idx >> 3, c8 = (idx & 7) * 8;
        u16x8 v;
        #pragma unroll
        for (int j = 0; j < 8; ++j) v[j] = tile[r][c8 + j];
        *(u16x8*)(vt + ((size_t)(bh * 64 + r)) * S_ + s0 + c8) = v;
    }
}

// ---------------------------------------------------------------------------
// LayerNorm row kernel: fp32 X row (1024) -> bf16 xn.  grid: B*S, block 256.
// ---------------------------------------------------------------------------
__global__ __launch_bounds__(256) void ln_kernel(
    const float* __restrict__ X, const float* __restrict__ g,
    const float* __restrict__ bp, u16* __restrict__ out)
{
    const int row = blockIdx.x, tid = threadIdx.x;
    const float* xr = X + (size_t)row * D_;
    f32x4 v = *(const f32x4*)(xr + tid * 4);
    float s  = v[0] + v[1] + v[2] + v[3];
    float s2 = v[0]*v[0] + v[1]*v[1] + v[2]*v[2] + v[3]*v[3];
    #pragma unroll
    for (int off = 32; off >= 1; off >>= 1) {
        s  += __shfl_down(s,  off);
        s2 += __shfl_down(s2, off);
    }
    __shared__ float red[8];
    const int lane = tid & 63, wid = tid >> 6;
    if (lane == 0) { red[wid] = s; red[4 + wid] = s2; }
    __syncthreads();
    s  = red[0] + red[1] + red[2] + red[3];
    s2 = red[4] + red[5] + red[6] + red[7];
    float mean = s * (1.f / D_);
    float var  = s2 * (1.f / D_) - mean * mean;
    float rstd = rsqrtf(var + 1e-5f);
    f32x4 gv = *(const f32x4*)(g  + tid * 4);
    f32x4 bv = *(const f32x4*)(bp + tid * 4);
    u16x4 o4;
    #pragma unroll
    for (int r = 0; r < 4; ++r) o4[r] = f2bf((v[r] - mean) * rstd * gv[r] + bv[r]);
    *(u16x4*)(out + (size_t)row * D_ + tid * 4) = o4;
}

// ---------------------------------------------------------------------------
// gemm256p: C[M][N] = A[M][K] * B^T[N][K], bf16 in, fp32 acc.
// 256x256 tile, BK=32, 8 waves (2M x 4N, per-wave C = 128x64).
// 4-deep pipeline over FOUR DISTINCT __shared__ arrays with the K-loop
// unrolled x4 so every buffer reference is a compile-time object: LLVM's
// LDS-DMA waitcnt insertion can then prove the ds_reads of buffer u don't
// alias the in-flight global_load_lds to buffers u+1..u+3, and only our
// counted vmcnt(8/4/0) orders the pipeline (T3+T4).  One s_barrier per tile.
// T2 swizzle (both sides, r2-verified 0 conflicts).  T5 setprio on MFMA.
// T1: bijective XCD swizzle on the linearized block id.
// Requires NT = Kh/32 to be a multiple of 4, >= 8.
// MODE: 0=+bias->bf16 (QKV), 1=+bias,pad-mask,atomic X+= (out-proj),
//       2=+bias,GELU->bf16 (FC1), 3=+bias,atomic X+= (FC2)
// ---------------------------------------------------------------------------
template<int MODE>
__global__ __launch_bounds__(512, 2) void gemm256p(
    const u16* __restrict__ A, const u16* __restrict__ BT,
    const float* __restrict__ bias,
    u16* __restrict__ Cb, float* __restrict__ X,
    const int* __restrict__ lengths,
    int M, int N, int K)
{
    __shared__ __align__(16) char sb0[32768];   // [A 16K | B 16K] per tile
    __shared__ __align__(16) char sb1[32768];
    __shared__ __align__(16) char sb2[32768];
    __shared__ __align__(16) char sb3[32768];

    const int tid = threadIdx.x;
    const int lane = tid & 63;
    const int w = tid >> 6;
    const int grp = lane >> 4, l15 = lane & 15;
    const int wm = w >> 2, wn = w & 3;

    // ---- T1: bijective XCD swizzle (m204) ----
    const int gx = gridDim.x, gy = gridDim.y;
    const int nwg = gx * gy * gridDim.z;
    int lid = blockIdx.x + gx * (blockIdx.y + gy * blockIdx.z);
    {
        int q = nwg >> 3, r = nwg & 7;
        int xcd = lid & 7, wi = lid >> 3;
        lid = (xcd < r ? xcd * (q + 1) : r * (q + 1) + (xcd - r) * q) + wi;
    }
    const int bx = lid % gx;
    const int byz = lid / gx;
    const int by = byz % gy, bz = byz / gy;

    const int m0 = by * 256, n0 = bx * 256;
    const int Kh = K / gridDim.z;
    const int k0 = bz * Kh;
    const int NT = Kh >> 5;                        // K-tiles of 32 (mult of 4, >=8)

    // staging: each wave stages 32 A-rows and 32 B-rows (2 gloads each)
    const int lrow = lane >> 2;
    const int cchunk = (lane & 3) ^ ((lane >> 3) & 3);  // pre-swizzled source chunk
    const u16* gA = A  + (size_t)(m0 + w * 32 + lrow) * K + k0 + cchunk * 8;
    const u16* gB = BT + (size_t)(n0 + w * 32 + lrow) * K + k0 + cchunk * 8;
    const size_t row16 = (size_t)16 * K;
    const int rslot = (grp ^ ((l15 >> 1) & 3)) * 16;    // swizzled read slot

#define STAGE(t, BUF) do {                                                    \
        const u16* pa_ = gA + (size_t)(t) * 32;                               \
        const u16* pb_ = gB + (size_t)(t) * 32;                               \
        char* la_ = (BUF) + w * 2048;                                         \
        char* lb_ = (BUF) + 16384 + w * 2048;                                 \
        gload16(pa_, la_); gload16(pa_ + row16, la_ + 1024);                  \
        gload16(pb_, lb_); gload16(pb_ + row16, lb_ + 1024); } while (0)

    f32x4 acc[8][4] = {};

#define TILEBODY(CUR, WAITSTR, STAGE_STMT) do {                               \
        asm volatile(WAITSTR ::: "memory");                                   \
        __builtin_amdgcn_s_barrier();                                         \
        __builtin_amdgcn_sched_barrier(0);                                    \
        const char* Ab_ = (CUR);                                              \
        const char* Bb_ = (CUR) + 16384;                                      \
        bf16x8 bfr_[4], af0_[4], af1_[4];                                     \
        _Pragma("unroll")                                                     \
        for (int nf = 0; nf < 4; ++nf)                                        \
            bfr_[nf] = *(const bf16x8*)(Bb_ + (wn * 64 + nf * 16 + l15) * 64 + rslot); \
        _Pragma("unroll")                                                     \
        for (int mf = 0; mf < 4; ++mf)                                        \
            af0_[mf] = *(const bf16x8*)(Ab_ + (wm * 128 + mf * 16 + l15) * 64 + rslot); \
        _Pragma("unroll")                                                     \
        for (int mf = 0; mf < 4; ++mf)                                        \
            af1_[mf] = *(const bf16x8*)(Ab_ + (wm * 128 + 64 + mf * 16 + l15) * 64 + rslot); \
        STAGE_STMT;                                                           \
        __builtin_amdgcn_s_setprio(1);                                        \
        _Pragma("unroll")                                                     \
        for (int mf = 0; mf < 4; ++mf)                                        \
            _Pragma("unroll")                                                 \
            for (int nf = 0; nf < 4; ++nf)                                    \
                acc[mf][nf] = __builtin_amdgcn_mfma_f32_16x16x32_bf16(        \
                    af0_[mf], bfr_[nf], acc[mf][nf], 0, 0, 0);                \
        _Pragma("unroll")                                                     \
        for (int mf = 0; mf < 4; ++mf)                                        \
            _Pragma("unroll")                                                 \
            for (int nf = 0; nf < 4; ++nf)                                    \
                acc[4 + mf][nf] = __builtin_amdgcn_mfma_f32_16x16x32_bf16(    \
                    af1_[mf], bfr_[nf], acc[4 + mf][nf], 0, 0, 0);            \
        __builtin_amdgcn_s_setprio(0);                                        \
    } while (0)

    STAGE(0, sb0);
    STAGE(1, sb1);
    STAGE(2, sb2);

    int t = 0;
    for (; t + 4 < NT; t += 4) {
        TILEBODY(sb0, "s_waitcnt vmcnt(8)", STAGE(t + 3, sb3));
        TILEBODY(sb1, "s_waitcnt vmcnt(8)", STAGE(t + 4, sb0));
        TILEBODY(sb2, "s_waitcnt vmcnt(8)", STAGE(t + 5, sb1));
        TILEBODY(sb3, "s_waitcnt vmcnt(8)", STAGE(t + 6, sb2));
    }
    // t == NT-4 here (NT % 4 == 0)
    TILEBODY(sb0, "s_waitcnt vmcnt(8)", STAGE(t + 3, sb3));
    TILEBODY(sb1, "s_waitcnt vmcnt(8)", (void)0);
    TILEBODY(sb2, "s_waitcnt vmcnt(4)", (void)0);
    TILEBODY(sb3, "s_waitcnt vmcnt(0)", (void)0);
#undef TILEBODY
#undef STAGE

    const float bscale = (k0 == 0) ? 1.f : 0.f;    // bias exactly once per output
    // C/D frag: col = lane&15, row = (lane>>4)*4 + reg  [HW-verified]
    #pragma unroll
    for (int mi = 0; mi < 8; ++mi) {
        int row_g = m0 + wm * 128 + mi * 16 + grp * 4;
        #pragma unroll
        for (int nf = 0; nf < 4; ++nf) {
            int col_g = n0 + wn * 64 + nf * 16 + l15;
            float bv = bias[col_g] * bscale;
            f32x4 v = acc[mi][nf];
            if constexpr (MODE == 0) {
                #pragma unroll
                for (int r = 0; r < 4; ++r)
                    Cb[(size_t)(row_g + r) * N + col_g] = f2bf(v[r] + bv);
            } else if constexpr (MODE == 2) {
                #pragma unroll
                for (int r = 0; r < 4; ++r) {
                    float tv = v[r] + bv;
                    float ge = 0.5f * tv * (1.f + erff(tv * 0.70710678118654752f));
                    Cb[(size_t)(row_g + r) * N + col_g] = f2bf(ge);
                }
            } else if constexpr (MODE == 1) {
                int len = lengths[row_g >> 10];      // row_g%4==0: same batch
                #pragma unroll
                for (int r = 0; r < 4; ++r) {
                    int row = row_g + r;
                    float add = ((row & 1023) >= len) ? 0.f : (v[r] + bv);
                    atomicAdd(&X[(size_t)row * N + col_g], add);
                }
            } else {
                #pragma unroll
                for (int r = 0; r < 4; ++r)
                    atomicAdd(&X[(size_t)(row_g + r) * N + col_g], v[r] + bv);
            }
        }
    }
}

// ---------------------------------------------------------------------------
// Flash attention with rel_bias + causal + key-padding masks (unchanged).
// ---------------------------------------------------------------------------
__global__ __launch_bounds__(256) void attn_kernel(
    const u16* __restrict__ qkv,
    const u16* __restrict__ vt,
    const float* __restrict__ rel_bias,
    const int* __restrict__ lengths,
    u16* __restrict__ obuf)
{
    __shared__ __align__(16) char kls[64 * 128];
    __shared__ __align__(16) char vls[64 * 128];
    const int tid = threadIdx.x, lane = tid & 63, wid = tid >> 6;
    const int grp = lane >> 4, l15 = lane & 15;
    const int qt = blockIdx.x, bh = blockIdx.y;
    const int b = bh >> 4, h = bh & 15;
    const int len = lengths[b];
    const int qrow = qt * 64 + wid * 16 + l15;

    bf16x8 qf[2];
    {
        const u16* qp = qkv + ((size_t)(b * S_ + qrow)) * D3_ + h * 64 + grp * 8;
        qf[0] = *(const bf16x8*)qp;
        qf[1] = *(const bf16x8*)(qp + 32);
    }
    f32x4 oacc[4] = {};
    float m_run = -INFINITY, lsum = 0.f;
    int kt_end = (len + 63) >> 6;
    if (qt + 1 < kt_end) kt_end = qt + 1;

    for (int kt = 0; kt < kt_end; ++kt) {
        __syncthreads();
        #pragma unroll
        for (int i = 0; i < 2; ++i) {
            int id2 = tid + i * 256;
            int r = id2 >> 3, gg = id2 & 7;
            int sw = (r & 7) << 4;
            bf16x8 kv = *(const bf16x8*)(qkv + ((size_t)(b * S_ + kt * 64 + r)) * D3_ + D_ + h * 64 + gg * 8);
            *(bf16x8*)(kls + r * 128 + ((gg * 16) ^ sw)) = kv;
            bf16x8 vv = *(const bf16x8*)(vt + ((size_t)(bh * 64 + r)) * S_ + kt * 64 + gg * 8);
            *(bf16x8*)(vls + r * 128 + ((gg * 16) ^ sw)) = vv;
        }
        __syncthreads();

        f32x4 sf[4] = {};
        #pragma unroll
        for (int f = 0; f < 4; ++f) {
            int r = f * 16 + l15;
            int sw = (r & 7) << 4;
            #pragma unroll
            for (int t = 0; t < 2; ++t) {
                bf16x8 af = *(const bf16x8*)(kls + r * 128 + (((t * 32 + grp * 8) * 2) ^ sw));
                sf[f] = __builtin_amdgcn_mfma_f32_16x16x32_bf16(af, qf[t], sf[f], 0, 0, 0);
            }
        }
        float p[4][4];
        float tmax = -INFINITY;
        #pragma unroll
        for (int f = 0; f < 4; ++f) {
            f32x4 bi = *(const f32x4*)(rel_bias + ((size_t)h * S_ + qrow) * S_ + kt * 64 + f * 16 + grp * 4);
            #pragma unroll
            for (int r = 0; r < 4; ++r) {
                int kp = kt * 64 + f * 16 + grp * 4 + r;
                bool valid = (kp <= qrow) && (kp < len);
                float sv = valid ? fmaf(sf[f][r], 0.125f, bi[r]) : -INFINITY;
                p[f][r] = sv;
                tmax = fmaxf(tmax, sv);
            }
        }
        tmax = fmaxf(tmax, __shfl_xor(tmax, 16));
        tmax = fmaxf(tmax, __shfl_xor(tmax, 32));
        float m_new = fmaxf(m_run, tmax);
        float alpha = expf(m_run - m_new);
        float psum = 0.f;
        #pragma unroll
        for (int f = 0; f < 4; ++f)
            #pragma unroll
            for (int r = 0; r < 4; ++r) {
                float e = expf(p[f][r] - m_new);
                p[f][r] = e; psum += e;
            }
        psum += __shfl_xor(psum, 16);
        psum += __shfl_xor(psum, 32);
        lsum = lsum * alpha + psum;
        m_run = m_new;
        #pragma unroll
        for (int fo = 0; fo < 4; ++fo) {
            oacc[fo][0] *= alpha; oacc[fo][1] *= alpha;
            oacc[fo][2] *= alpha; oacc[fo][3] *= alpha;
        }
        #pragma unroll
        for (int t = 0; t < 2; ++t) {
            union { u16 u[8]; bf16x8 v; } pb;
            #pragma unroll
            for (int j = 0; j < 4; ++j) {
                pb.u[j]     = f2bf(p[2 * t][j]);
                pb.u[4 + j] = f2bf(p[2 * t + 1][j]);
            }
            #pragma unroll
            for (int fo = 0; fo < 4; ++fo) {
                int r = fo * 16 + l15;
                int sw = (r & 7) << 4;
                union { u16x4 h4[2]; bf16x8 v; } av;
                av.h4[0] = *(const u16x4*)(vls + r * 128 + ((t * 64 + grp * 8)      ^ sw));
                av.h4[1] = *(const u16x4*)(vls + r * 128 + ((t * 64 + grp * 8 + 32) ^ sw));
                oacc[fo] = __builtin_amdgcn_mfma_f32_16x16x32_bf16(av.v, pb.v, oacc[fo], 0, 0, 0);
            }
        }
    }
    float inv = 1.f / lsum;
    #pragma unroll
    for (int fo = 0; fo < 4; ++fo)
        #pragma unroll
        for (int r = 0; r < 4; ++r) {
            int hd = fo * 16 + grp * 4 + r;
            obuf[((size_t)(b * S_) + qrow) * D_ + h * 64 + hd] = f2bf(oacc[fo][r] * inv);
        }
}

// ---------------------------------------------------------------------------
extern "C" void kernel_launch(void* const* d_in, const int* in_sizes, int n_in,
                              void* d_out, int out_size, void* d_ws, size_t ws_size,
                              hipStream_t stream)
{
    const float* x_in     = (const float*)d_in[0];
    const int*   lengths  = (const int*)d_in[1];
    const float* rel_bias = (const float*)d_in[2];
    const float* ln1_g    = (const float*)d_in[3];
    const float* ln1_b    = (const float*)d_in[4];
    const float* qkv_w    = (const float*)d_in[5];
    const float* qkv_b    = (const float*)d_in[6];
    const float* out_w    = (const float*)d_in[7];
    const float* out_b    = (const float*)d_in[8];
    const float* ln2_g    = (const float*)d_in[9];
    const float* ln2_b    = (const float*)d_in[10];
    const float* fc1_w    = (const float*)d_in[11];
    const float* fc1_b    = (const float*)d_in[12];
    const float* fc2_w    = (const float*)d_in[13];
    const float* fc2_b    = (const float*)d_in[14];
    float* X = (float*)d_out;     // running residual state, fp32

    char* ws = (char*)d_ws;
    size_t off = 0;
    auto alloc = [&](size_t bytes) {
        char* p = ws + off;
        off = (off + bytes + 255) & ~(size_t)255;
        return p;
    };
    u16* wT_qkv = (u16*)alloc((size_t)D3_ * D_ * 2);
    u16* wT_out = (u16*)alloc((size_t)D_ * D_ * 2);
    u16* wT_fc1 = (u16*)alloc((size_t)FF_ * D_ * 2);
    u16* wT_fc2 = (u16*)alloc((size_t)D_ * FF_ * 2);
    u16* xn     = (u16*)alloc((size_t)B_ * S_ * D_ * 2);
    u16* qkvb   = (u16*)alloc((size_t)B_ * S_ * D3_ * 2);
    u16* vtb    = (u16*)alloc((size_t)B_ * H_ * HD_ * S_ * 2);
    u16* ob     = (u16*)alloc((size_t)B_ * S_ * D_ * 2);
    u16* h1     = (u16*)alloc((size_t)B_ * S_ * FF_ * 2);

    const int M = B_ * S_;  // 4096

    hipMemcpyAsync(X, x_in, (size_t)M * D_ * sizeof(float),
                   hipMemcpyDeviceToDevice, stream);

    for (int i = 0; i < L_; ++i) {
        cvt_layer<<<3072, 256, 0, stream>>>(
            qkv_w + (size_t)i * D_ * D3_, out_w + (size_t)i * D_ * D_,
            fc1_w + (size_t)i * D_ * FF_, fc2_w + (size_t)i * FF_ * D_,
            wT_qkv, wT_out, wT_fc1, wT_fc2);

        // --- attention sub-block ---
        ln_kernel<<<M, 256, 0, stream>>>(X, ln1_g + i * D_, ln1_b + i * D_, xn);
        gemm256p<0><<<dim3(D3_ / 256, M / 256, 1), 512, 0, stream>>>(
            xn, wT_qkv, qkv_b + (size_t)i * D3_, qkvb, nullptr, nullptr, M, D3_, D_);
        vt_transpose<<<dim3(S_ / 64, B_ * H_), 256, 0, stream>>>(qkvb, vtb);
        attn_kernel<<<dim3(S_ / 64, B_ * H_), 256, 0, stream>>>(
            qkvb, vtb, rel_bias, lengths, ob);
        gemm256p<1><<<dim3(D_ / 256, M / 256, 4), 512, 0, stream>>>(
            ob, wT_out, out_b + (size_t)i * D_, nullptr, X, lengths, M, D_, D_);

        // --- feed-forward sub-block ---
        ln_kernel<<<M, 256, 0, stream>>>(X, ln2_g + i * D_, ln2_b + i * D_, xn);
        gemm256p<2><<<dim3(FF_ / 256, M / 256, 1), 512, 0, stream>>>(
            xn, wT_fc1, fc1_b + (size_t)i * FF_, h1, nullptr, nullptr, M, FF_, D_);
        gemm256p<3><<<dim3(D_ / 256, M / 256, 4), 512, 0, stream>>>(
            h1, wT_fc2, fc2_b + (size_t)i * D_, nullptr, X, nullptr, M, D_, FF_);
    }
}